// Round 2
// baseline (1077.625 us; speedup 1.0000x reference)
//
#include <hip/hip_runtime.h>
#include <cstdint>

#define NN 8192
#define DD 256

typedef unsigned short u16;
typedef __bf16 bf16x8 __attribute__((ext_vector_type(8)));
typedef float f32x4 __attribute__((ext_vector_type(4)));

__device__ __forceinline__ u16 f2bf(float f) {
    union { float f; unsigned u; } c; c.f = f;
    unsigned u = c.u;
    return (u16)((u + 0x7FFFu + ((u >> 16) & 1u)) >> 16);   // RNE
}

// ---------------------------------------------------------------------------
// GEMM: C[M x 256] = A[M x K] * B[K x 256], B given transposed (BT[n][k], bf16).
// A fp32 (AF32=1, converted in-kernel) or bf16 (AF32=0).
// Tile 64(m) x 256(n) x 32(k-step); 4 waves; wave w owns n in [64w, 64w+64);
// each wave 4x4 frags of mfma_f32_16x16x32_bf16. grid=(M/64, 1, KSPLIT).
// ROWSUM: wave 0 also accumulates rowsum(A-tile) via ones-column B fragment.
// ---------------------------------------------------------------------------
template<bool AF32, bool ROWSUM, bool ATOMIC>
__global__ __launch_bounds__(256, 2)
void gemm_k(const void* __restrict__ Ap, long ldA,
            const u16* __restrict__ BT, long ldBT,
            float* __restrict__ C, float* __restrict__ rs, int kPer)
{
    __shared__ __align__(16) u16 As[64 * 32];     // 4 groups of 16 rows
    __shared__ __align__(16) u16 Bs[256 * 32];    // 16 groups

    const int tid  = threadIdx.x;
    const int lane = tid & 63;
    const int wave = tid >> 6;       // 0..3
    const int r    = lane & 15;
    const int q    = lane >> 4;
    const long m0  = (long)blockIdx.x * 64;
    const long k0  = (long)blockIdx.z * kPer;

    f32x4 acc[4][4] = {};
    f32x4 racc[4]   = {};
    bf16x8 ones;
    if constexpr (ROWSUM) {
        union { bf16x8 v; u16 u[8]; } cv;
        u16 pat = (r == 0) ? (u16)0x3F80 : (u16)0;   // 1.0 in n-col 0
        #pragma unroll
        for (int j = 0; j < 8; ++j) cv.u[j] = pat;
        ones = cv.v;
    }

    // B staging: wave loads groups 4w..4w+3 (rows wave*64 + g2*16 + r)
    const u16* bBase = BT + (long)(wave * 64 + r) * ldBT + k0 + q * 8;
    // A staging (AF32): thread t handles row t>>2, k-octet t&3 (8 fp32 -> 8 bf16)
    const int arow = tid >> 2;
    const int kq8  = tid & 3;
    const float* aBaseF = AF32 ? ((const float*)Ap + (m0 + arow) * ldA + k0 + kq8 * 8) : nullptr;
    // A staging (bf16): wave loads group `wave` via global_load_lds
    const u16* aBaseH = AF32 ? nullptr
                             : ((const u16*)Ap + (m0 + wave * 16 + r) * ldA + k0 + q * 8);
    const int nsteps = kPer >> 5;

    for (int s = 0; s < nsteps; ++s) {
        const long koff = (long)s << 5;
        if constexpr (AF32) {
            const float* ap = aBaseF + koff;
            float4 f0 = *(const float4*)ap;
            float4 f1 = *(const float4*)(ap + 4);
            union { u16 u[8]; uint4 v; } pk;
            pk.u[0] = f2bf(f0.x); pk.u[1] = f2bf(f0.y);
            pk.u[2] = f2bf(f0.z); pk.u[3] = f2bf(f0.w);
            pk.u[4] = f2bf(f1.x); pk.u[5] = f2bf(f1.y);
            pk.u[6] = f2bf(f1.z); pk.u[7] = f2bf(f1.w);
            // chunk: group g=arow>>4, slot l = kq8*16 + (arow&15)
            *(uint4*)(As + (arow >> 4) * 512 + (kq8 * 16 + (arow & 15)) * 8) = pk.v;
        } else {
            __builtin_amdgcn_global_load_lds(
                (const __attribute__((address_space(1))) void*)(aBaseH + koff),
                (__attribute__((address_space(3))) void*)(As + wave * 512 + lane * 8),
                16, 0, 0);
        }
        #pragma unroll
        for (int g2 = 0; g2 < 4; ++g2) {
            __builtin_amdgcn_global_load_lds(
                (const __attribute__((address_space(1))) void*)(bBase + (long)g2 * 16 * ldBT + koff),
                (__attribute__((address_space(3))) void*)(Bs + (wave * 4 + g2) * 512 + lane * 8),
                16, 0, 0);
        }
        __syncthreads();

        bf16x8 af[4], bfr[4];
        #pragma unroll
        for (int i = 0; i < 4; ++i) {
            af[i]  = *(const bf16x8*)(As + i * 512 + lane * 8);
            bfr[i] = *(const bf16x8*)(Bs + (wave * 4 + i) * 512 + lane * 8);
        }
        #pragma unroll
        for (int i = 0; i < 4; ++i)
            #pragma unroll
            for (int j = 0; j < 4; ++j)
                acc[i][j] = __builtin_amdgcn_mfma_f32_16x16x32_bf16(af[i], bfr[j], acc[i][j], 0, 0, 0);
        if constexpr (ROWSUM) {
            if (wave == 0) {
                #pragma unroll
                for (int i = 0; i < 4; ++i)
                    racc[i] = __builtin_amdgcn_mfma_f32_16x16x32_bf16(af[i], ones, racc[i], 0, 0, 0);
            }
        }
        __syncthreads();
    }

    // epilogue: C/D layout col = lane&15, row = (lane>>4)*4 + reg
    #pragma unroll
    for (int i = 0; i < 4; ++i) {
        const long rowb = m0 + i * 16 + q * 4;
        #pragma unroll
        for (int j = 0; j < 4; ++j) {
            const long col = wave * 64 + j * 16 + r;
            #pragma unroll
            for (int rr2 = 0; rr2 < 4; ++rr2) {
                float v = acc[i][j][rr2];
                float* p = C + (rowb + rr2) * DD + col;
                if constexpr (ATOMIC) atomicAdd(p, v); else *p = v;
            }
        }
        if constexpr (ROWSUM) {
            if (wave == 0 && r == 0) {
                #pragma unroll
                for (int rr2 = 0; rr2 < 4; ++rr2)
                    atomicAdd(rs + rowb + rr2, racc[i][rr2]);
            }
        }
    }
}

// ---------------------------------------------------------------------------
// transpose-convert: src fp32 [R][C] -> dst bf16 [C][R]. 64x64 tiles.
// ---------------------------------------------------------------------------
__global__ __launch_bounds__(256)
void tc_k(const float* __restrict__ src, u16* __restrict__ dst, int R, int C)
{
    __shared__ u16 t[64][72];
    const int tid = threadIdx.x;
    const int rr = tid >> 2;
    const int cc = (tid & 3) << 4;
    const long r0 = (long)blockIdx.x * 64;
    const long c0 = (long)blockIdx.y * 64;
    const float* sp = src + (r0 + rr) * C + c0 + cc;
    #pragma unroll
    for (int j = 0; j < 16; ++j) t[cc + j][rr] = f2bf(sp[j]);
    __syncthreads();
    u16* dp = dst + (c0 + rr) * (long)R + r0 + cc;
    #pragma unroll
    for (int j = 0; j < 16; ++j) dp[j] = t[rr][cc + j];
}

// ---------------------------------------------------------------------------
// norm0: v = (resid + Cacc) * 1/(rs+1); write outF fp32 [N][256] AND
// outT bf16 [256][N] (transposed). 64x64 tiles.
// ---------------------------------------------------------------------------
__global__ __launch_bounds__(256)
void norm0_k(const float* __restrict__ Cacc, const float* __restrict__ rs,
             const float* __restrict__ resid,
             float* __restrict__ outF, u16* __restrict__ outT)
{
    __shared__ u16 t[64][72];
    const int tid = threadIdx.x;
    const int rr = tid >> 2;
    const int cc = (tid & 3) << 4;
    const long i0 = (long)blockIdx.x * 64;
    const int  n0 = blockIdx.y * 64;
    const long i  = i0 + rr;
    const float scale = 1.0f / (rs[i] + 1.0f);
    const float* cp = Cacc + i * DD + n0 + cc;
    const float* rp = resid + i * DD + n0 + cc;
    float* fp = outF + i * DD + n0 + cc;
    #pragma unroll
    for (int j = 0; j < 16; ++j) {
        float v = (rp[j] + cp[j]) * scale;
        fp[j] = v;
        t[cc + j][rr] = f2bf(v);
    }
    __syncthreads();
    u16* op = outT + (long)(n0 + rr) * NN + i0 + cc;
    #pragma unroll
    for (int j = 0; j < 16; ++j) op[j] = t[rr][cc + j];
}

// ---------------------------------------------------------------------------
// norm1: v = (resid + Cacc) * 1/(rs+1); write bf16 row-major [N][256].
// grid 2048 x 256thr, 4 elems/thread.
// ---------------------------------------------------------------------------
__global__ __launch_bounds__(256)
void norm1_k(const float* __restrict__ Cacc, const float* __restrict__ rs,
             const float* __restrict__ resid, u16* __restrict__ outR)
{
    const long g = ((long)blockIdx.x * 256 + threadIdx.x) * 4;
    const long row = g >> 8;
    const float scale = 1.0f / (rs[row] + 1.0f);
    const float4 c = *(const float4*)(Cacc + g);
    const float4 rv = *(const float4*)(resid + g);
    u16* op = outR + g;
    op[0] = f2bf((rv.x + c.x) * scale);
    op[1] = f2bf((rv.y + c.y) * scale);
    op[2] = f2bf((rv.z + c.z) * scale);
    op[3] = f2bf((rv.w + c.w) * scale);
}

// ---------------------------------------------------------------------------
// GCN helpers
// ---------------------------------------------------------------------------
__global__ __launch_bounds__(256)
void count_k(const int* __restrict__ dst, int E, int* __restrict__ counts) {
    int e = blockIdx.x * 256 + threadIdx.x;
    if (e < E) atomicAdd(counts + dst[e], 1);
}

__global__ __launch_bounds__(256)
void scan_k(const int* __restrict__ counts, int* __restrict__ offs,
            int* __restrict__ cursor, float* __restrict__ dinv) {
    __shared__ int sh[256];
    __shared__ int sbase;
    const int tid = threadIdx.x;
    if (tid == 0) sbase = 0;
    __syncthreads();
    for (int base = 0; base < NN; base += 256) {
        int c = counts[base + tid];
        dinv[base + tid] = 1.0f / sqrtf((float)c + 1.0f);
        sh[tid] = c;
        __syncthreads();
        #pragma unroll
        for (int off2 = 1; off2 < 256; off2 <<= 1) {
            int v = (tid >= off2) ? sh[tid - off2] : 0;
            __syncthreads();
            sh[tid] += v;
            __syncthreads();
        }
        int excl = sbase + sh[tid] - c;
        offs[base + tid] = excl;
        cursor[base + tid] = excl;
        int tot = sh[255];
        __syncthreads();
        if (tid == 0) sbase += tot;
        __syncthreads();
    }
    if (tid == 0) offs[NN] = sbase;
}

__global__ __launch_bounds__(256)
void fill_k(const int* __restrict__ src, const int* __restrict__ dst, int E,
            int* __restrict__ cursor, int* __restrict__ csr) {
    int e = blockIdx.x * 256 + threadIdx.x;
    if (e < E) {
        int p = atomicAdd(cursor + dst[e], 1);
        csr[p] = src[e];
    }
}

// ---------------------------------------------------------------------------
// gather: out[i] = b + dinv[i]^2*h[i] + sum_{e:dst=i} dinv[i]*dinv[src]*h[src]
// one wave per node, lane owns 4 features. outBF (bf16) or outF (fp32).
// ---------------------------------------------------------------------------
__global__ __launch_bounds__(256)
void gather_k(const float* __restrict__ h,
              const int* __restrict__ offs,
              const int* __restrict__ csr,
              const float* __restrict__ dinv,
              const float* __restrict__ bias,
              u16* __restrict__ outBF,
              float* __restrict__ outF)
{
    const int node = blockIdx.x * 4 + (threadIdx.x >> 6);
    const int lane = threadIdx.x & 63;
    const float di = dinv[node];
    const float4 hs = ((const float4*)(h + (long)node * DD))[lane];
    const float s0 = di * di;
    float4 acc;
    acc.x = hs.x * s0; acc.y = hs.y * s0; acc.z = hs.z * s0; acc.w = hs.w * s0;

    const int b0 = offs[node], b1 = offs[node + 1];
    for (int e = b0; e < b1; ++e) {
        const int s = csr[e];
        const float w = di * dinv[s];
        const float4 x = ((const float4*)(h + (long)s * DD))[lane];
        acc.x += w * x.x; acc.y += w * x.y; acc.z += w * x.z; acc.w += w * x.w;
    }
    const float4 bv = ((const float4*)bias)[lane];
    acc.x += bv.x; acc.y += bv.y; acc.z += bv.z; acc.w += bv.w;

    if (outF) {
        ((float4*)(outF + (long)node * DD))[lane] = acc;
    } else {
        u16* op = outBF + (long)node * DD + lane * 4;
        op[0] = f2bf(acc.x); op[1] = f2bf(acc.y);
        op[2] = f2bf(acc.z); op[3] = f2bf(acc.w);
    }
}

// ---------------------------------------------------------------------------
extern "C" void kernel_launch(void* const* d_in, const int* in_sizes, int n_in,
                              void* d_out, int out_size, void* d_ws, size_t ws_size,
                              hipStream_t stream)
{
    (void)n_in; (void)out_size; (void)ws_size;
    const float* emb0  = (const float*)d_in[0];
    const float* A     = (const float*)d_in[1];
    const int*   eiS   = (const int*)d_in[2];
    const int*   eiU   = (const int*)d_in[3];
    const float* Wsame = (const float*)d_in[4];
    const float* bsame = (const float*)d_in[5];
    const float* Wtop  = (const float*)d_in[6];
    const float* btop  = (const float*)d_in[7];
    const int E = in_sizes[2] / 2;

    char* ws = (char*)d_ws;
    u16*   embT   = (u16*)  (ws + 0);          // 4 MiB  [256][8192] bf16
    float* Cacc   = (float*)(ws + 4194304);    // 8 MiB  [8192][256] f32
    float* emb1   = (float*)(ws + 12582912);   // 8 MiB  [8192][256] f32
    u16*   xbf    = (u16*)  (ws + 20971520);   // 4 MiB  [8192][256] bf16
    u16*   WT     = (u16*)  (ws + 25165824);   // 128 KiB [256][256] bf16
    float* rsb    = (float*)(ws + 25296896);   // 32 KiB
    float* dinv   = (float*)(ws + 25329664);   // 32 KiB
    int*   counts = (int*)  (ws + 25362432);   // 32 KiB
    int*   offs   = (int*)  (ws + 25395200);   // 36 KiB (NN+1 ints)
    int*   cursor = (int*)  (ws + 25432064);   // 32 KiB
    int*   csr    = (int*)  (ws + 25464832);   // 512 KiB

    const dim3 blk(256);
    const dim3 gDense(128, 1, 4), gGcn(128, 1, 1);
    const dim3 gE((E + 255) / 256), gG(NN / 4);

    // embT = bf16(emb0)^T
    tc_k<<<dim3(128, 4), blk, 0, stream>>>(emb0, embT, NN, DD);

    // ---- level 0
    hipMemsetAsync(Cacc, 0, 8388608, stream);
    hipMemsetAsync(rsb, 0, 32768, stream);
    gemm_k<true, true, true><<<gDense, blk, 0, stream>>>(A, NN, embT, NN, Cacc, rsb, 2048);
    norm0_k<<<dim3(128, 4), blk, 0, stream>>>(Cacc, rsb, emb0, emb1, embT);

    // ---- level 1
    hipMemsetAsync(Cacc, 0, 8388608, stream);
    hipMemsetAsync(rsb, 0, 32768, stream);
    gemm_k<true, true, true><<<gDense, blk, 0, stream>>>(A + (size_t)NN * NN, NN, embT, NN, Cacc, rsb, 2048);
    norm1_k<<<dim3(2048), blk, 0, stream>>>(Cacc, rsb, emb1, xbf);

    // ---- GCN layer 1 (same_level)
    tc_k<<<dim3(4, 4), blk, 0, stream>>>(Wsame, WT, DD, DD);
    hipMemsetAsync(counts, 0, 32768, stream);
    count_k<<<gE, blk, 0, stream>>>(eiS + E, E, counts);
    scan_k<<<dim3(1), blk, 0, stream>>>(counts, offs, cursor, dinv);
    fill_k<<<gE, blk, 0, stream>>>(eiS, eiS + E, E, cursor, csr);
    gemm_k<false, false, false><<<gGcn, blk, 0, stream>>>(xbf, DD, WT, DD, Cacc, nullptr, 256);
    gather_k<<<gG, blk, 0, stream>>>(Cacc, offs, csr, dinv, bsame, xbf, nullptr);

    // ---- GCN layer 2 (up2down)
    tc_k<<<dim3(4, 4), blk, 0, stream>>>(Wtop, WT, DD, DD);
    hipMemsetAsync(counts, 0, 32768, stream);
    count_k<<<gE, blk, 0, stream>>>(eiU + E, E, counts);
    scan_k<<<dim3(1), blk, 0, stream>>>(counts, offs, cursor, dinv);
    fill_k<<<gE, blk, 0, stream>>>(eiU, eiU + E, E, cursor, csr);
    gemm_k<false, false, false><<<gGcn, blk, 0, stream>>>(xbf, DD, WT, DD, Cacc, nullptr, 256);
    gather_k<<<gG, blk, 0, stream>>>(Cacc, offs, csr, dinv, btop, nullptr, (float*)d_out);
}